// Round 22
// baseline (63.773 us; speedup 1.0000x reference)
//
#include <hip/hip_runtime.h>
#include <hip/hip_bf16.h>

#define EPS 1e-5f
#define SLOPE 0.01f

typedef __attribute__((ext_vector_type(8))) short bfrag8;   // 8 bf16 (4 VGPRs)
typedef __attribute__((ext_vector_type(4))) float f32x4;

#define AS1 __attribute__((address_space(1)))
#define AS3 __attribute__((address_space(3)))

// ---- workspace byte offsets ----
#define WS_SIM_OFF   0u          // [1024][16] f32 (zeroed by prep; gemm atomicAdds)
#define WS_S_OFF     65536u      // [1024][16] f32
#define WS_WVS_OFF   131072u     // [2048][16] f32, transposed [c][n]
#define WS_BVS_OFF   262144u     // [16] f32
#define WS_AIMG_OFF  262208u     // bf16 A image, swizzle-baked: [src2][mt16][kt32][p512]x16B = 8,388,608 B
#define WS_BIMG_OFF  8650816u    // bf16 B image, swizzle-baked: [h16][dh2][kt32][p512]x16B = 8,388,608 B
                                  //   B tile cols: cit<32 -> q col h*64+dh*32+cit ; cit>=32 -> k col h*128+dh*32+(cit-32)

// round-to-nearest-even fp32 -> bf16
__device__ __forceinline__ unsigned short f2bf(float f) {
    union { float f; unsigned int u; } x; x.f = f;
    unsigned int r = (x.u + 0x7FFFu + ((x.u >> 16) & 1u)) >> 16;
    return (unsigned short)r;
}
__device__ __forceinline__ uint4 pack8(const float4& a, const float4& b) {
    uint4 r;
    r.x = (unsigned)f2bf(a.x) | ((unsigned)f2bf(a.y) << 16);
    r.y = (unsigned)f2bf(a.z) | ((unsigned)f2bf(a.w) << 16);
    r.z = (unsigned)f2bf(b.x) | ((unsigned)f2bf(b.y) << 16);
    r.w = (unsigned)f2bf(b.z) | ((unsigned)f2bf(b.w) << 16);
    return r;
}

// ---------------- kernel 0: prep — swizzle-baked images + WvS + sim-zero + bvS ----------------
#define PREP_A    524288
#define PREP_B2   (PREP_A + 524288)
#define PREP_WVSE (PREP_B2 + 32768)
#define PREP_SIMZ (PREP_WVSE + 16384)
#define PREP_END  (PREP_SIMZ + 16)

__global__ __launch_bounds__(256) void prep_kernel(
        const float* __restrict__ qin, const float* __restrict__ kvin,
        const float* __restrict__ Wq, const float* __restrict__ Wkv,
        const float* __restrict__ bkv, unsigned char* __restrict__ ws) {
    int gid = blockIdx.x * 256 + threadIdx.x;
    if (gid < PREP_A) {
        int p  = gid & 511;
        int kt = (gid >> 9) & 31;
        int mt = (gid >> 14) & 15;
        int s2 = gid >> 18;                    // 0 = q_input, 1 = kv_input
        int rit = p >> 3;
        int gk = (p & 7) ^ (rit & 7);
        int row = mt * 64 + rit;
        int k = kt * 64 + gk * 8;
        const float* src = (s2 ? kvin : qin) + (size_t)row * 2048 + k;
        float4 v0 = *(const float4*)src;
        float4 v1 = *(const float4*)(src + 4);
        *(uint4*)(ws + WS_AIMG_OFF + (size_t)gid * 16) = pack8(v0, v1);
    } else if (gid < PREP_B2) {
        int g2 = gid - PREP_A;
        int p  = g2 & 511;
        int kt = (g2 >> 9) & 31;
        int dh = (g2 >> 14) & 1;
        int h  = g2 >> 15;
        int cit = p >> 3;                      // 0..63: <32 q-col, >=32 k-col
        int gk = (p & 7) ^ (cit & 7);
        int k = kt * 64 + gk * 8;
        const float* wrow;
        if (cit < 32) wrow = Wq  + (size_t)(h * 64 + dh * 32 + cit) * 2048;
        else          wrow = Wkv + (size_t)(h * 128 + dh * 32 + (cit - 32)) * 2048;
        float4 v0 = *(const float4*)(wrow + k);
        float4 v1 = *(const float4*)(wrow + k + 4);
        *(uint4*)(ws + WS_BIMG_OFF + (size_t)g2 * 16) = pack8(v0, v1);
    } else if (gid < PREP_WVSE) {
        int g2 = gid - PREP_B2;
        int n = g2 >> 11, c = g2 & 2047;
        const float* base = Wkv + (size_t)(n * 128 + 64) * 2048 + c;
        float s = 0.f;
        #pragma unroll 8
        for (int d = 0; d < 64; ++d) s += base[(size_t)d * 2048];
        ((float*)(ws + WS_WVS_OFF))[c * 16 + n] = s;
    } else if (gid < PREP_SIMZ) {
        ((float*)(ws + WS_SIM_OFF))[gid - PREP_WVSE] = 0.f;
    } else if (gid < PREP_END) {
        int n = gid - PREP_SIMZ;
        float b = 0.f;
        #pragma unroll
        for (int d = 0; d < 64; ++d) b += bkv[n * 128 + 64 + d];
        ((float*)(ws + WS_BVS_OFF))[n] = b;
    }
}

// ---------------- kernel 1: fused q/k projection + dot — dual-head, PAIR-PHASES ----------------
// grid (x = hp 8, y = mt 16, z = dh 2) = 256 blocks (1/CU), 512 thr = 8 waves
// (qk = w>>2, hh = (w>>1)&1, wr = w&1). r21 change: 16 phases x BK=128 — stage a
// PAIR of k-tiles (8 DMAs/thread) before two COMPUTEs (256 MFMAs) whose latency
// hides the stage; vmcnt(0)+barrier once per pair (fixed per-barrier overhead
// amortized over 2 tiles). 2 pair-buffers (128 KB LDS), WAR sealed by the
// previous phase's barrier. Full-K per-wave accumulation THEN pairing
// (bilinear-exact); dh-split exact; sim gets 2 commutative atomicAdds/cell.
__global__ __launch_bounds__(512, 1) void gemm_sim_kernel(unsigned char* __restrict__ ws,
        const float* __restrict__ bq, const float* __restrict__ bkv) {
    __shared__ alignas(16) unsigned short LAq[2][2][4096];      // 32 KB [buf][sub][..]
    __shared__ alignas(16) unsigned short LAkv[2][2][4096];     // 32 KB
    __shared__ alignas(16) unsigned short LB[2][2][2][4096];    // 64 KB [buf][sub][hh][..]

    const int t = threadIdx.x;
    const int w = t >> 6, l = t & 63;
    const int hp = blockIdx.x, mt = blockIdx.y, dh = blockIdx.z;
    const int qk = w >> 2, hh = (w >> 1) & 1, wr = w & 1;
    const int h = hp * 2 + hh;
    const int lrow = l & 15, lhi = l >> 4;
    const int m0 = mt * 64;

    const unsigned char* aqBase = ws + WS_AIMG_OFF + (size_t)mt * 262144u;
    const unsigned char* akBase = aqBase + 4194304u;
    const unsigned char* bBase0 = ws + WS_BIMG_OFF + (size_t)((hp * 2 + 0) * 2 + dh) * 262144u;
    const unsigned char* bBase1 = ws + WS_BIMG_OFF + (size_t)((hp * 2 + 1) * 2 + dh) * 262144u;
    float* sim = (float*)(ws + WS_SIM_OFF);

    // swizzled ds_read byte offsets (slot = (ks*4+lhi) ^ (idx&7))
    int offA[2][2], offB[2][2];
    #pragma unroll
    for (int ks = 0; ks < 2; ++ks)
        #pragma unroll
        for (int i = 0; i < 2; ++i) {
            int r = wr * 32 + i * 16 + lrow;            // A row
            int c = qk * 32 + i * 16 + lrow;            // B col within hh tile
            offA[ks][i] = r * 128 + (((ks * 4 + lhi) ^ (r & 7)) << 4);
            offB[ks][i] = c * 128 + (((ks * 4 + lhi) ^ (c & 7)) << 4);
        }

    f32x4 acc00 = (f32x4)0.f, acc01 = (f32x4)0.f, acc10 = (f32x4)0.f, acc11 = (f32x4)0.f;

// stage ONE k-tile (4 DMAs/thread) into [buf][sub]
#define STAGE1(kt_, buf_, sub_) do {                                                 \
    const unsigned char* _aq = aqBase + (size_t)(kt_) * 8192 + t * 16;               \
    const unsigned char* _ak = akBase + (size_t)(kt_) * 8192 + t * 16;               \
    const unsigned char* _b0 = bBase0 + (size_t)(kt_) * 8192 + t * 16;               \
    const unsigned char* _b1 = bBase1 + (size_t)(kt_) * 8192 + t * 16;               \
    unsigned char* _dq = ((unsigned char*)&LAq[0][0][0])  + (size_t)((buf_) * 2 + (sub_)) * 8192 + t * 16; \
    unsigned char* _dk = ((unsigned char*)&LAkv[0][0][0]) + (size_t)((buf_) * 2 + (sub_)) * 8192 + t * 16; \
    unsigned char* _d0 = ((unsigned char*)&LB[0][0][0][0]) + (size_t)((buf_) * 2 + (sub_)) * 16384 + t * 16;        \
    unsigned char* _d1 = ((unsigned char*)&LB[0][0][0][0]) + (size_t)((buf_) * 2 + (sub_)) * 16384 + 8192 + t * 16; \
    __builtin_amdgcn_global_load_lds((const AS1 unsigned int*)(const void*)_aq,      \
        (AS3 unsigned int*)(void*)_dq, 16, 0, 0);                                    \
    __builtin_amdgcn_global_load_lds((const AS1 unsigned int*)(const void*)_ak,      \
        (AS3 unsigned int*)(void*)_dk, 16, 0, 0);                                    \
    __builtin_amdgcn_global_load_lds((const AS1 unsigned int*)(const void*)_b0,      \
        (AS3 unsigned int*)(void*)_d0, 16, 0, 0);                                    \
    __builtin_amdgcn_global_load_lds((const AS1 unsigned int*)(const void*)_b1,      \
        (AS3 unsigned int*)(void*)_d1, 16, 0, 0);                                    \
    } while (0)

#define COMPUTE(buf_, sub_) do {                                                     \
    const char* Ab = (const char*)(qk ? &LAkv[0][0][0] : &LAq[0][0][0])              \
                   + ((buf_) * 2 + (sub_)) * 8192;                                   \
    const char* Bb = (const char*)&LB[0][0][0][0] + ((buf_) * 2 + (sub_)) * 16384 + hh * 8192; \
    _Pragma("unroll")                                                                \
    for (int ks = 0; ks < 2; ++ks) {                                                 \
        bfrag8 fa0 = *(const bfrag8*)(Ab + offA[ks][0]);                             \
        bfrag8 fa1 = *(const bfrag8*)(Ab + offA[ks][1]);                             \
        bfrag8 fb0 = *(const bfrag8*)(Bb + offB[ks][0]);                             \
        bfrag8 fb1 = *(const bfrag8*)(Bb + offB[ks][1]);                             \
        acc00 = __builtin_amdgcn_mfma_f32_16x16x32_bf16(fa0, fb0, acc00, 0, 0, 0);   \
        acc01 = __builtin_amdgcn_mfma_f32_16x16x32_bf16(fa0, fb1, acc01, 0, 0, 0);   \
        acc10 = __builtin_amdgcn_mfma_f32_16x16x32_bf16(fa1, fb0, acc10, 0, 0, 0);   \
        acc11 = __builtin_amdgcn_mfma_f32_16x16x32_bf16(fa1, fb1, acc11, 0, 0, 0);   \
    } } while (0)

    // ---- prologue: stage pair 0 (tiles 0,1) into buf 0 ----
    STAGE1(0, 0, 0);
    STAGE1(1, 0, 1);
    asm volatile("s_waitcnt vmcnt(0)" ::: "memory");
    __builtin_amdgcn_sched_barrier(0);
    __builtin_amdgcn_s_barrier();
    __builtin_amdgcn_sched_barrier(0);

    // ---- main loop: 16 pair-phases; stage next pair BEFORE compute (latency hidden) ----
    for (int p = 0; p < 16; ++p) {
        const int buf = p & 1;
        if (p < 15) {
            STAGE1(2 * p + 2, buf ^ 1, 0);   // WAR-safe: buf^1 last read in phase p-1,
            STAGE1(2 * p + 3, buf ^ 1, 1);   //   sealed behind that phase's barrier
        }
        COMPUTE(buf, 0);                     // tile 2p
        COMPUTE(buf, 1);                     // tile 2p+1 (~256 MFMAs hide stage latency)
        asm volatile("s_waitcnt vmcnt(0)" ::: "memory");
        __builtin_amdgcn_sched_barrier(0);
        __builtin_amdgcn_s_barrier();
        __builtin_amdgcn_sched_barrier(0);
    }
#undef STAGE1
#undef COMPUTE

    // ---- epilogue: +bias (fp32 exact), pair Cq*Ck via LDS, reduce over d, atomicAdd sim ----
    f32x4 acc[2][2] = {{acc00, acc01}, {acc10, acc11}};
    float biasv[2];
    #pragma unroll
    for (int ni = 0; ni < 2; ++ni) {
        int d = dh * 32 + ni * 16 + lrow;
        biasv[ni] = qk ? bkv[h * 128 + d] : bq[h * 64 + d];
    }
    #pragma unroll
    for (int mi = 0; mi < 2; ++mi)
        #pragma unroll
        for (int ni = 0; ni < 2; ++ni)
            #pragma unroll
            for (int r = 0; r < 4; ++r)
                acc[mi][ni][r] += biasv[ni];

    float* cqs = (float*)&LAq[0][0][0];   // reuse 16 KB of staging LDS: [hh][wr][32][32]
    if (!qk) {
        #pragma unroll
        for (int mi = 0; mi < 2; ++mi)
            #pragma unroll
            for (int ni = 0; ni < 2; ++ni)
                #pragma unroll
                for (int r = 0; r < 4; ++r) {
                    int row = mi * 16 + lhi * 4 + r;
                    cqs[(((hh * 2 + wr) * 32 + row) * 32) + ni * 16 + lrow] = acc[mi][ni][r];
                }
    }
    __syncthreads();
    if (qk) {
        #pragma unroll
        for (int mi = 0; mi < 2; ++mi) {
            float pv[4];
            #pragma unroll
            for (int r = 0; r < 4; ++r) {
                int row = mi * 16 + lhi * 4 + r;
                const float* crow = cqs + ((hh * 2 + wr) * 32 + row) * 32;
                pv[r] = crow[lrow] * acc[mi][0][r] + crow[16 + lrow] * acc[mi][1][r];
            }
            #pragma unroll
            for (int r = 0; r < 4; ++r) {
                float v = pv[r];
                v += __shfl_xor(v, 1); v += __shfl_xor(v, 2);
                v += __shfl_xor(v, 4); v += __shfl_xor(v, 8);
                if ((l & 15) == 0) {
                    int row = wr * 32 + mi * 16 + (l >> 4) * 4 + r;
                    atomicAdd(&sim[(m0 + row) * 16 + h], v);   // 2 adds/cell (dh halves)
                }
            }
        }
    }
}

// ---------------- kernel 2: S[b][n] = kv_input[b]·WvS[:,n] + bvS[n] (fp32) ----------------
__global__ __launch_bounds__(256) void s_kernel(
        const float* __restrict__ kvin, unsigned char* __restrict__ ws) {
    int b = blockIdx.x, t = threadIdx.x;
    int w = t >> 6, l = t & 63;
    __shared__ float SW[4][16];
    int n = t & 15, g = t >> 4;
    const float* kvrow = kvin + (size_t)b * 2048;
    const float* wv = (const float*)(ws + WS_WVS_OFF);
    float p = 0.f;
    #pragma unroll 4
    for (int tt = 0; tt < 128; ++tt) {
        int c = g + (tt << 4);
        p = fmaf(kvrow[c], wv[c * 16 + n], p);
    }
    p += __shfl_xor(p, 16);
    p += __shfl_xor(p, 32);
    if (l < 16) SW[w][n] = p;
    __syncthreads();
    if (t < 16) {
        float sv = SW[0][t] + SW[1][t] + SW[2][t] + SW[3][t]
                 + ((const float*)(ws + WS_BVS_OFF))[t];
        ((float*)(ws + WS_S_OFF))[b * 16 + t] = sv;
    }
}

// ---------------- kernel 3: softmax, A-reduce, pooled, leaky, batchnorm, output ----------------
__global__ __launch_bounds__(1024) void final_kernel(
        const float* __restrict__ bn_w, const float* __restrict__ bn_b,
        const float* __restrict__ Wo, const float* __restrict__ bo,
        const unsigned char* __restrict__ ws, float* __restrict__ out) {
    int t = threadIdx.x;
    int w = t >> 6;
    int l = t & 63;
    __shared__ float Aw[16][16];
    __shared__ float Af[4][16];
    __shared__ float SWs[16][8];
    __shared__ float FS[8];
    __shared__ float sc[4], sh[4];

    float a16[16];
    {
        const float* srow = (const float*)(ws + WS_SIM_OFF) + (size_t)t * 16;
        float4 v0 = *(const float4*)(srow + 0);
        float4 v1 = *(const float4*)(srow + 4);
        float4 v2 = *(const float4*)(srow + 8);
        float4 v3 = *(const float4*)(srow + 12);
        a16[0]=v0.x; a16[1]=v0.y; a16[2]=v0.z; a16[3]=v0.w;
        a16[4]=v1.x; a16[5]=v1.y; a16[6]=v1.z; a16[7]=v1.w;
        a16[8]=v2.x; a16[9]=v2.y; a16[10]=v2.z; a16[11]=v2.w;
        a16[12]=v3.x; a16[13]=v3.y; a16[14]=v3.z; a16[15]=v3.w;
        float m = a16[0];
        #pragma unroll
        for (int n = 1; n < 16; ++n) m = fmaxf(m, a16[n]);
        float den = 0.f;
        #pragma unroll
        for (int n = 0; n < 16; ++n) { a16[n] = expf(a16[n] - m); den += a16[n]; }
        float inv = 1.f / den;
        #pragma unroll
        for (int n = 0; n < 16; ++n) a16[n] *= inv;
    }
    #pragma unroll
    for (int n = 0; n < 16; ++n) {
        float p = a16[n];
        p += __shfl_xor(p, 1);  p += __shfl_xor(p, 2);
        p += __shfl_xor(p, 4);  p += __shfl_xor(p, 8);
        p += __shfl_xor(p, 16); p += __shfl_xor(p, 32);
        a16[n] = p;
    }
    if (l == 0) {
        #pragma unroll
        for (int n = 0; n < 16; ++n) Aw[w][n] = a16[n];
    }
    __syncthreads();
    if (t < 64) {
        int f = t >> 4, n = t & 15;
        Af[f][n] = Aw[4*f][n] + Aw[4*f+1][n] + Aw[4*f+2][n] + Aw[4*f+3][n];
    }
    __syncthreads();

    float sv[16];
    {
        const float* srow = (const float*)(ws + WS_S_OFF) + (size_t)t * 16;
        float4 v0 = *(const float4*)(srow + 0);
        float4 v1 = *(const float4*)(srow + 4);
        float4 v2 = *(const float4*)(srow + 8);
        float4 v3 = *(const float4*)(srow + 12);
        sv[0]=v0.x; sv[1]=v0.y; sv[2]=v0.z; sv[3]=v0.w;
        sv[4]=v1.x; sv[5]=v1.y; sv[6]=v1.z; sv[7]=v1.w;
        sv[8]=v2.x; sv[9]=v2.y; sv[10]=v2.z; sv[11]=v2.w;
        sv[12]=v3.x; sv[13]=v3.y; sv[14]=v3.z; sv[15]=v3.w;
    }
    float x[4];
    #pragma unroll
    for (int f = 0; f < 4; ++f) {
        float p = 0.f;
        #pragma unroll
        for (int n = 0; n < 16; ++n) p = fmaf(Af[f][n], sv[n], p);
        p *= (1.f / 16384.f);
        x[f] = (p >= 0.f) ? p : SLOPE * p;
    }

    float st[8];
    #pragma unroll
    for (int f = 0; f < 4; ++f) { st[f] = x[f]; st[4 + f] = x[f] * x[f]; }
    #pragma unroll
    for (int j = 0; j < 8; ++j) {
        float p = st[j];
        p += __shfl_xor(p, 1);  p += __shfl_xor(p, 2);
        p += __shfl_xor(p, 4);  p += __shfl_xor(p, 8);
        p += __shfl_xor(p, 16); p += __shfl_xor(p, 32);
        st[j] = p;
    }
    if (l == 0) {
        #pragma unroll
        for (int j = 0; j < 8; ++j) SWs[w][j] = st[j];
    }
    __syncthreads();
    if (t < 8) {
        float p = 0.f;
        #pragma unroll
        for (int ww = 0; ww < 16; ++ww) p += SWs[ww][t];
        FS[t] = p;
    }
    __syncthreads();
    if (t < 4) {
        float mean = FS[t] * (1.f / 1024.f);
        float var  = FS[4 + t] * (1.f / 1024.f) - mean * mean;
        float s = bn_w[t] / sqrtf(var + EPS);
        sc[t] = s;
        sh[t] = bn_b[t] - mean * s;
    }
    __syncthreads();

    float o0 = bo[0], o1 = bo[1];
    #pragma unroll
    for (int f = 0; f < 4; ++f) {
        float xh = x[f] * sc[f] + sh[f];
        o0 = fmaf(xh, Wo[f], o0);
        o1 = fmaf(xh, Wo[4 + f], o1);
    }
    *(float2*)(out + (size_t)t * 2) = make_float2(o0, o1);
}

// ---------------- launch ----------------
extern "C" void kernel_launch(void* const* d_in, const int* in_sizes, int n_in,
                              void* d_out, int out_size, void* d_ws, size_t ws_size,
                              hipStream_t stream) {
    const float* q_input  = (const float*)d_in[0];
    const float* kv_input = (const float*)d_in[1];
    const float* Wq   = (const float*)d_in[2];
    const float* bq   = (const float*)d_in[3];
    const float* Wkv  = (const float*)d_in[4];
    const float* bkv  = (const float*)d_in[5];
    const float* bn_w = (const float*)d_in[6];
    const float* bn_b = (const float*)d_in[7];
    const float* Wo   = (const float*)d_in[8];
    const float* bo   = (const float*)d_in[9];
    float* out = (float*)d_out;
    unsigned char* ws = (unsigned char*)d_ws;

    hipLaunchKernelGGL(prep_kernel, dim3((PREP_END + 255) / 256), dim3(256), 0, stream,
                       q_input, kv_input, Wq, Wkv, bkv, ws);
    hipLaunchKernelGGL(gemm_sim_kernel, dim3(8, 16, 2), dim3(512), 0, stream,
                       ws, bq, bkv);
    hipLaunchKernelGGL(s_kernel, dim3(1024), dim3(256), 0, stream, kv_input, ws);
    hipLaunchKernelGGL(final_kernel, dim3(1), dim3(1024), 0, stream,
                       bn_w, bn_b, Wo, bo, ws, out);
}

// Round 23
// 59.693 us; speedup vs baseline: 1.0683x; 1.0683x over previous
//
#include <hip/hip_runtime.h>
#include <hip/hip_bf16.h>

#define EPS 1e-5f
#define SLOPE 0.01f

typedef __attribute__((ext_vector_type(8))) short bfrag8;   // 8 bf16 (4 VGPRs)
typedef __attribute__((ext_vector_type(4))) float f32x4;

#define AS1 __attribute__((address_space(1)))
#define AS3 __attribute__((address_space(3)))

// ---- workspace byte offsets ----
#define WS_SIM_OFF   0u          // [1024][16] f32 (zeroed by prep; gemm atomicAdds)
#define WS_S_OFF     65536u      // [1024][16] f32
#define WS_WVS_OFF   131072u     // [2048][16] f32, transposed [c][n]
#define WS_BVS_OFF   262144u     // [16] f32
#define WS_AIMG_OFF  262208u     // bf16 A image, swizzle-baked: [src2][mt16][kt32][p512]x16B = 8,388,608 B
#define WS_BIMG_OFF  8650816u    // bf16 B image, swizzle-baked: [h16][dh2][kt32][p512]x16B = 8,388,608 B
                                  //   B tile cols: cit<32 -> q col h*64+dh*32+cit ; cit>=32 -> k col h*128+dh*32+(cit-32)

// round-to-nearest-even fp32 -> bf16
__device__ __forceinline__ unsigned short f2bf(float f) {
    union { float f; unsigned int u; } x; x.f = f;
    unsigned int r = (x.u + 0x7FFFu + ((x.u >> 16) & 1u)) >> 16;
    return (unsigned short)r;
}
__device__ __forceinline__ uint4 pack8(const float4& a, const float4& b) {
    uint4 r;
    r.x = (unsigned)f2bf(a.x) | ((unsigned)f2bf(a.y) << 16);
    r.y = (unsigned)f2bf(a.z) | ((unsigned)f2bf(a.w) << 16);
    r.z = (unsigned)f2bf(b.x) | ((unsigned)f2bf(b.y) << 16);
    r.w = (unsigned)f2bf(b.z) | ((unsigned)f2bf(b.w) << 16);
    return r;
}

// ---------------- kernel 0: prep — swizzle-baked images + WvS + sim-zero + bvS ----------------
#define PREP_A    524288
#define PREP_B2   (PREP_A + 524288)
#define PREP_WVSE (PREP_B2 + 32768)
#define PREP_SIMZ (PREP_WVSE + 16384)
#define PREP_END  (PREP_SIMZ + 16)

__global__ __launch_bounds__(256) void prep_kernel(
        const float* __restrict__ qin, const float* __restrict__ kvin,
        const float* __restrict__ Wq, const float* __restrict__ Wkv,
        const float* __restrict__ bkv, unsigned char* __restrict__ ws) {
    int gid = blockIdx.x * 256 + threadIdx.x;
    if (gid < PREP_A) {
        int p  = gid & 511;
        int kt = (gid >> 9) & 31;
        int mt = (gid >> 14) & 15;
        int s2 = gid >> 18;                    // 0 = q_input, 1 = kv_input
        int rit = p >> 3;
        int gk = (p & 7) ^ (rit & 7);
        int row = mt * 64 + rit;
        int k = kt * 64 + gk * 8;
        const float* src = (s2 ? kvin : qin) + (size_t)row * 2048 + k;
        float4 v0 = *(const float4*)src;
        float4 v1 = *(const float4*)(src + 4);
        *(uint4*)(ws + WS_AIMG_OFF + (size_t)gid * 16) = pack8(v0, v1);
    } else if (gid < PREP_B2) {
        int g2 = gid - PREP_A;
        int p  = g2 & 511;
        int kt = (g2 >> 9) & 31;
        int dh = (g2 >> 14) & 1;
        int h  = g2 >> 15;
        int cit = p >> 3;                      // 0..63: <32 q-col, >=32 k-col
        int gk = (p & 7) ^ (cit & 7);
        int k = kt * 64 + gk * 8;
        const float* wrow;
        if (cit < 32) wrow = Wq  + (size_t)(h * 64 + dh * 32 + cit) * 2048;
        else          wrow = Wkv + (size_t)(h * 128 + dh * 32 + (cit - 32)) * 2048;
        float4 v0 = *(const float4*)(wrow + k);
        float4 v1 = *(const float4*)(wrow + k + 4);
        *(uint4*)(ws + WS_BIMG_OFF + (size_t)g2 * 16) = pack8(v0, v1);
    } else if (gid < PREP_WVSE) {
        int g2 = gid - PREP_B2;
        int n = g2 >> 11, c = g2 & 2047;
        const float* base = Wkv + (size_t)(n * 128 + 64) * 2048 + c;
        float s = 0.f;
        #pragma unroll 8
        for (int d = 0; d < 64; ++d) s += base[(size_t)d * 2048];
        ((float*)(ws + WS_WVS_OFF))[c * 16 + n] = s;
    } else if (gid < PREP_SIMZ) {
        ((float*)(ws + WS_SIM_OFF))[gid - PREP_WVSE] = 0.f;
    } else if (gid < PREP_END) {
        int n = gid - PREP_SIMZ;
        float b = 0.f;
        #pragma unroll
        for (int d = 0; d < 64; ++d) b += bkv[n * 128 + 64 + d];
        ((float*)(ws + WS_BVS_OFF))[n] = b;
    }
}

// ---------------- kernel 1: fused q/k projection + dot — DUAL-HEAD blocks (r19 best) ----------------
// grid (x = hp 8, y = mt 16, z = dh 2) = 256 blocks (1/CU), 512 thr = 8 waves.
// Wave w: qk = w>>2 (0=q,1=k), hh = (w>>1)&1 (head in pair), wr = w&1 (row half).
// One A staging serves TWO heads: per k-step stage Aq 8 + Akv 8 + B 16 = 32 KB
// (4 DMAs/thread) and run 128 MFMAs. Full-K per-wave accumulation THEN pairing
// (bilinear-exact); d-split (dh) exact; sim gets 2 commutative atomicAdds/cell.
// 3-buffer depth-2 counted vmcnt(4) (never 0 in main loop).
__global__ __launch_bounds__(512, 1) void gemm_sim_kernel(unsigned char* __restrict__ ws,
        const float* __restrict__ bq, const float* __restrict__ bkv) {
    __shared__ alignas(16) unsigned short LAq[3][4096];      // 24 KB
    __shared__ alignas(16) unsigned short LAkv[3][4096];     // 24 KB
    __shared__ alignas(16) unsigned short LB[3][2][4096];    // 48 KB [buf][hh][..]

    const int t = threadIdx.x;
    const int w = t >> 6, l = t & 63;
    const int hp = blockIdx.x, mt = blockIdx.y, dh = blockIdx.z;
    const int qk = w >> 2, hh = (w >> 1) & 1, wr = w & 1;
    const int h = hp * 2 + hh;
    const int lrow = l & 15, lhi = l >> 4;
    const int m0 = mt * 64;

    const unsigned char* aqBase = ws + WS_AIMG_OFF + (size_t)mt * 262144u;
    const unsigned char* akBase = aqBase + 4194304u;
    const unsigned char* bBase0 = ws + WS_BIMG_OFF + (size_t)((hp * 2 + 0) * 2 + dh) * 262144u;
    const unsigned char* bBase1 = ws + WS_BIMG_OFF + (size_t)((hp * 2 + 1) * 2 + dh) * 262144u;
    float* sim = (float*)(ws + WS_SIM_OFF);

    // swizzled ds_read byte offsets (slot = (ks*4+lhi) ^ (idx&7))
    int offA[2][2], offB[2][2];
    #pragma unroll
    for (int ks = 0; ks < 2; ++ks)
        #pragma unroll
        for (int i = 0; i < 2; ++i) {
            int r = wr * 32 + i * 16 + lrow;            // A row
            int c = qk * 32 + i * 16 + lrow;            // B col within hh tile
            offA[ks][i] = r * 128 + (((ks * 4 + lhi) ^ (r & 7)) << 4);
            offB[ks][i] = c * 128 + (((ks * 4 + lhi) ^ (c & 7)) << 4);
        }

    f32x4 acc00 = (f32x4)0.f, acc01 = (f32x4)0.f, acc10 = (f32x4)0.f, acc11 = (f32x4)0.f;

#define STAGE(kt_, buf_) do {                                                        \
    const unsigned char* _aq = aqBase + (size_t)(kt_) * 8192 + t * 16;               \
    const unsigned char* _ak = akBase + (size_t)(kt_) * 8192 + t * 16;               \
    const unsigned char* _b0 = bBase0 + (size_t)(kt_) * 8192 + t * 16;               \
    const unsigned char* _b1 = bBase1 + (size_t)(kt_) * 8192 + t * 16;               \
    unsigned char* _dq = ((unsigned char*)&LAq[0][0])  + (size_t)(buf_) * 8192 + t * 16;  \
    unsigned char* _dk = ((unsigned char*)&LAkv[0][0]) + (size_t)(buf_) * 8192 + t * 16;  \
    unsigned char* _d0 = ((unsigned char*)&LB[0][0][0]) + (size_t)(buf_) * 16384 + t * 16;        \
    unsigned char* _d1 = ((unsigned char*)&LB[0][0][0]) + (size_t)(buf_) * 16384 + 8192 + t * 16; \
    __builtin_amdgcn_global_load_lds((const AS1 unsigned int*)(const void*)_aq,      \
        (AS3 unsigned int*)(void*)_dq, 16, 0, 0);                                    \
    __builtin_amdgcn_global_load_lds((const AS1 unsigned int*)(const void*)_ak,      \
        (AS3 unsigned int*)(void*)_dk, 16, 0, 0);                                    \
    __builtin_amdgcn_global_load_lds((const AS1 unsigned int*)(const void*)_b0,      \
        (AS3 unsigned int*)(void*)_d0, 16, 0, 0);                                    \
    __builtin_amdgcn_global_load_lds((const AS1 unsigned int*)(const void*)_b1,      \
        (AS3 unsigned int*)(void*)_d1, 16, 0, 0);                                    \
    } while (0)

    // ---- prologue: stage tiles 0,1; force 0 complete, leave 1 in flight ----
    STAGE(0, 0);
    STAGE(1, 1);
    asm volatile("s_waitcnt vmcnt(4)" ::: "memory");
    __builtin_amdgcn_sched_barrier(0);
    __builtin_amdgcn_s_barrier();
    __builtin_amdgcn_sched_barrier(0);

    int cur = 0, nxt = 2;
    for (int kt = 0; kt < 32; ++kt) {
        // ---- compute k-tile kt from buffer cur ----
        {
            const char* Ab = (const char*)(qk ? &LAkv[0][0] : &LAq[0][0]) + cur * 8192;
            const char* Bb = (const char*)&LB[0][0][0] + cur * 16384 + hh * 8192;
            #pragma unroll
            for (int ks = 0; ks < 2; ++ks) {
                bfrag8 fa0 = *(const bfrag8*)(Ab + offA[ks][0]);
                bfrag8 fa1 = *(const bfrag8*)(Ab + offA[ks][1]);
                bfrag8 fb0 = *(const bfrag8*)(Bb + offB[ks][0]);
                bfrag8 fb1 = *(const bfrag8*)(Bb + offB[ks][1]);
                acc00 = __builtin_amdgcn_mfma_f32_16x16x32_bf16(fa0, fb0, acc00, 0, 0, 0);
                acc01 = __builtin_amdgcn_mfma_f32_16x16x32_bf16(fa0, fb1, acc01, 0, 0, 0);
                acc10 = __builtin_amdgcn_mfma_f32_16x16x32_bf16(fa1, fb0, acc10, 0, 0, 0);
                acc11 = __builtin_amdgcn_mfma_f32_16x16x32_bf16(fa1, fb1, acc11, 0, 0, 0);
            }
        }
        // ---- issue stage kt+2; counted wait keeps newest stage in flight ----
        if (kt < 30) {
            STAGE(kt + 2, nxt);
            asm volatile("s_waitcnt vmcnt(4)" ::: "memory");
        } else {
            asm volatile("s_waitcnt vmcnt(0)" ::: "memory");
        }
        __builtin_amdgcn_sched_barrier(0);
        __builtin_amdgcn_s_barrier();
        __builtin_amdgcn_sched_barrier(0);
        cur = (cur == 2) ? 0 : cur + 1;
        nxt = (nxt == 2) ? 0 : nxt + 1;
    }
#undef STAGE

    // ---- epilogue: +bias (fp32 exact), pair Cq*Ck via LDS, reduce over d, atomicAdd sim ----
    f32x4 acc[2][2] = {{acc00, acc01}, {acc10, acc11}};
    float biasv[2];
    #pragma unroll
    for (int ni = 0; ni < 2; ++ni) {
        int d = dh * 32 + ni * 16 + lrow;
        biasv[ni] = qk ? bkv[h * 128 + d] : bq[h * 64 + d];
    }
    #pragma unroll
    for (int mi = 0; mi < 2; ++mi)
        #pragma unroll
        for (int ni = 0; ni < 2; ++ni)
            #pragma unroll
            for (int r = 0; r < 4; ++r)
                acc[mi][ni][r] += biasv[ni];

    float* cqs = (float*)&LAq[0][0];   // reuse 16 KB of staging LDS: [hh][wr][32][32]
    if (!qk) {
        #pragma unroll
        for (int mi = 0; mi < 2; ++mi)
            #pragma unroll
            for (int ni = 0; ni < 2; ++ni)
                #pragma unroll
                for (int r = 0; r < 4; ++r) {
                    int row = mi * 16 + lhi * 4 + r;
                    cqs[(((hh * 2 + wr) * 32 + row) * 32) + ni * 16 + lrow] = acc[mi][ni][r];
                }
    }
    __syncthreads();
    if (qk) {
        #pragma unroll
        for (int mi = 0; mi < 2; ++mi) {
            float pv[4];
            #pragma unroll
            for (int r = 0; r < 4; ++r) {
                int row = mi * 16 + lhi * 4 + r;
                const float* crow = cqs + ((hh * 2 + wr) * 32 + row) * 32;
                pv[r] = crow[lrow] * acc[mi][0][r] + crow[16 + lrow] * acc[mi][1][r];
            }
            #pragma unroll
            for (int r = 0; r < 4; ++r) {
                float v = pv[r];
                v += __shfl_xor(v, 1); v += __shfl_xor(v, 2);
                v += __shfl_xor(v, 4); v += __shfl_xor(v, 8);
                if ((l & 15) == 0) {
                    int row = wr * 32 + mi * 16 + (l >> 4) * 4 + r;
                    atomicAdd(&sim[(m0 + row) * 16 + h], v);   // 2 adds/cell (dh halves)
                }
            }
        }
    }
}

// ---------------- kernel 2: S[b][n] = kv_input[b]·WvS[:,n] + bvS[n] (fp32) ----------------
__global__ __launch_bounds__(256) void s_kernel(
        const float* __restrict__ kvin, unsigned char* __restrict__ ws) {
    int b = blockIdx.x, t = threadIdx.x;
    int w = t >> 6, l = t & 63;
    __shared__ float SW[4][16];
    int n = t & 15, g = t >> 4;
    const float* kvrow = kvin + (size_t)b * 2048;
    const float* wv = (const float*)(ws + WS_WVS_OFF);
    float p = 0.f;
    #pragma unroll 4
    for (int tt = 0; tt < 128; ++tt) {
        int c = g + (tt << 4);
        p = fmaf(kvrow[c], wv[c * 16 + n], p);
    }
    p += __shfl_xor(p, 16);
    p += __shfl_xor(p, 32);
    if (l < 16) SW[w][n] = p;
    __syncthreads();
    if (t < 16) {
        float sv = SW[0][t] + SW[1][t] + SW[2][t] + SW[3][t]
                 + ((const float*)(ws + WS_BVS_OFF))[t];
        ((float*)(ws + WS_S_OFF))[b * 16 + t] = sv;
    }
}

// ---------------- kernel 3: softmax, A-reduce, pooled, leaky, batchnorm, output ----------------
__global__ __launch_bounds__(1024) void final_kernel(
        const float* __restrict__ bn_w, const float* __restrict__ bn_b,
        const float* __restrict__ Wo, const float* __restrict__ bo,
        const unsigned char* __restrict__ ws, float* __restrict__ out) {
    int t = threadIdx.x;
    int w = t >> 6;
    int l = t & 63;
    __shared__ float Aw[16][16];
    __shared__ float Af[4][16];
    __shared__ float SWs[16][8];
    __shared__ float FS[8];
    __shared__ float sc[4], sh[4];

    float a16[16];
    {
        const float* srow = (const float*)(ws + WS_SIM_OFF) + (size_t)t * 16;
        float4 v0 = *(const float4*)(srow + 0);
        float4 v1 = *(const float4*)(srow + 4);
        float4 v2 = *(const float4*)(srow + 8);
        float4 v3 = *(const float4*)(srow + 12);
        a16[0]=v0.x; a16[1]=v0.y; a16[2]=v0.z; a16[3]=v0.w;
        a16[4]=v1.x; a16[5]=v1.y; a16[6]=v1.z; a16[7]=v1.w;
        a16[8]=v2.x; a16[9]=v2.y; a16[10]=v2.z; a16[11]=v2.w;
        a16[12]=v3.x; a16[13]=v3.y; a16[14]=v3.z; a16[15]=v3.w;
        float m = a16[0];
        #pragma unroll
        for (int n = 1; n < 16; ++n) m = fmaxf(m, a16[n]);
        float den = 0.f;
        #pragma unroll
        for (int n = 0; n < 16; ++n) { a16[n] = expf(a16[n] - m); den += a16[n]; }
        float inv = 1.f / den;
        #pragma unroll
        for (int n = 0; n < 16; ++n) a16[n] *= inv;
    }
    #pragma unroll
    for (int n = 0; n < 16; ++n) {
        float p = a16[n];
        p += __shfl_xor(p, 1);  p += __shfl_xor(p, 2);
        p += __shfl_xor(p, 4);  p += __shfl_xor(p, 8);
        p += __shfl_xor(p, 16); p += __shfl_xor(p, 32);
        a16[n] = p;
    }
    if (l == 0) {
        #pragma unroll
        for (int n = 0; n < 16; ++n) Aw[w][n] = a16[n];
    }
    __syncthreads();
    if (t < 64) {
        int f = t >> 4, n = t & 15;
        Af[f][n] = Aw[4*f][n] + Aw[4*f+1][n] + Aw[4*f+2][n] + Aw[4*f+3][n];
    }
    __syncthreads();

    float sv[16];
    {
        const float* srow = (const float*)(ws + WS_S_OFF) + (size_t)t * 16;
        float4 v0 = *(const float4*)(srow + 0);
        float4 v1 = *(const float4*)(srow + 4);
        float4 v2 = *(const float4*)(srow + 8);
        float4 v3 = *(const float4*)(srow + 12);
        sv[0]=v0.x; sv[1]=v0.y; sv[2]=v0.z; sv[3]=v0.w;
        sv[4]=v1.x; sv[5]=v1.y; sv[6]=v1.z; sv[7]=v1.w;
        sv[8]=v2.x; sv[9]=v2.y; sv[10]=v2.z; sv[11]=v2.w;
        sv[12]=v3.x; sv[13]=v3.y; sv[14]=v3.z; sv[15]=v3.w;
    }
    float x[4];
    #pragma unroll
    for (int f = 0; f < 4; ++f) {
        float p = 0.f;
        #pragma unroll
        for (int n = 0; n < 16; ++n) p = fmaf(Af[f][n], sv[n], p);
        p *= (1.f / 16384.f);
        x[f] = (p >= 0.f) ? p : SLOPE * p;
    }

    float st[8];
    #pragma unroll
    for (int f = 0; f < 4; ++f) { st[f] = x[f]; st[4 + f] = x[f] * x[f]; }
    #pragma unroll
    for (int j = 0; j < 8; ++j) {
        float p = st[j];
        p += __shfl_xor(p, 1);  p += __shfl_xor(p, 2);
        p += __shfl_xor(p, 4);  p += __shfl_xor(p, 8);
        p += __shfl_xor(p, 16); p += __shfl_xor(p, 32);
        st[j] = p;
    }
    if (l == 0) {
        #pragma unroll
        for (int j = 0; j < 8; ++j) SWs[w][j] = st[j];
    }
    __syncthreads();
    if (t < 8) {
        float p = 0.f;
        #pragma unroll
        for (int ww = 0; ww < 16; ++ww) p += SWs[ww][t];
        FS[t] = p;
    }
    __syncthreads();
    if (t < 4) {
        float mean = FS[t] * (1.f / 1024.f);
        float var  = FS[4 + t] * (1.f / 1024.f) - mean * mean;
        float s = bn_w[t] / sqrtf(var + EPS);
        sc[t] = s;
        sh[t] = bn_b[t] - mean * s;
    }
    __syncthreads();

    float o0 = bo[0], o1 = bo[1];
    #pragma unroll
    for (int f = 0; f < 4; ++f) {
        float xh = x[f] * sc[f] + sh[f];
        o0 = fmaf(xh, Wo[f], o0);
        o1 = fmaf(xh, Wo[4 + f], o1);
    }
    *(float2*)(out + (size_t)t * 2) = make_float2(o0, o1);
}

// ---------------- launch ----------------
extern "C" void kernel_launch(void* const* d_in, const int* in_sizes, int n_in,
                              void* d_out, int out_size, void* d_ws, size_t ws_size,
                              hipStream_t stream) {
    const float* q_input  = (const float*)d_in[0];
    const float* kv_input = (const float*)d_in[1];
    const float* Wq   = (const float*)d_in[2];
    const float* bq   = (const float*)d_in[3];
    const float* Wkv  = (const float*)d_in[4];
    const float* bkv  = (const float*)d_in[5];
    const float* bn_w = (const float*)d_in[6];
    const float* bn_b = (const float*)d_in[7];
    const float* Wo   = (const float*)d_in[8];
    const float* bo   = (const float*)d_in[9];
    float* out = (float*)d_out;
    unsigned char* ws = (unsigned char*)d_ws;

    hipLaunchKernelGGL(prep_kernel, dim3((PREP_END + 255) / 256), dim3(256), 0, stream,
                       q_input, kv_input, Wq, Wkv, bkv, ws);
    hipLaunchKernelGGL(gemm_sim_kernel, dim3(8, 16, 2), dim3(512), 0, stream,
                       ws, bq, bkv);
    hipLaunchKernelGGL(s_kernel, dim3(1024), dim3(256), 0, stream, kv_input, ws);
    hipLaunchKernelGGL(final_kernel, dim3(1), dim3(1024), 0, stream,
                       bn_w, bn_b, Wo, bo, ws, out);
}